// Round 11
// baseline (417.863 us; speedup 1.0000x reference)
//
#include <hip/hip_runtime.h>

// Problem constants (fixed by the reference)
#define N_SRNA  20000
#define N_MRNA  100000
#define FDIM    128
#define NE      1000000
#define NQ      500000
#define NDST_ALL (N_MRNA + N_SRNA)

// Fixed-capacity buckets (no hist/scan prepass); see round-5 sigma analysis.
#define NB_M 196
#define NB_S 157
#define NB   (NB_M + NB_S)            // 353
#define NB_Q 196
#define ECAP 8192
#define QCAP 4096
#define NBLK_E 489                    // (2*NE + 4095) / 4096
#define NBLK_Q 123                    // (NQ + 4095) / 4096

typedef __attribute__((ext_vector_type(8))) short bf16x8;
typedef __attribute__((ext_vector_type(4))) float f32x4;

__device__ __forceinline__ unsigned short f2bf(float f) {
    unsigned int u = __float_as_uint(f);
    unsigned int r = (u + 0x7fffu + ((u >> 16) & 1u)) >> 16;   // RNE
    return (unsigned short)r;
}
__device__ __forceinline__ float bf2f(unsigned short h) {
    return __uint_as_float((unsigned int)h << 16);
}

// ---------------------------------------------------------------------------
// Combined binning scatter (unchanged)
// ---------------------------------------------------------------------------
__global__ __launch_bounds__(256) void k_scatter_all(const int* __restrict__ src_sm,
                                                     const int* __restrict__ dst_sm,
                                                     const int* __restrict__ src_ms,
                                                     const int* __restrict__ dst_ms,
                                                     const int* __restrict__ lbl_row,
                                                     const int* __restrict__ lbl_col,
                                                     int* __restrict__ bcur,
                                                     int* __restrict__ qbcur,
                                                     unsigned int* __restrict__ recs,
                                                     uint2* __restrict__ qrecs) {
    __shared__ int lh[NB], gb[NB], lc[NB];
    int t = threadIdx.x;
    if ((int)blockIdx.x < NBLK_E) {
        for (int i = t; i < NB; i += 256) { lh[i] = 0; lc[i] = 0; }
        __syncthreads();
        unsigned int rec[16];
        int bk[16];
        int i0 = blockIdx.x * 4096;
#pragma unroll
        for (int j = 0; j < 16; ++j) {
            int i = i0 + j * 256 + t;
            int b = -1; unsigned int r = 0;
            if (i < NE) {
                int d = dst_sm[i];
                b = d >> 9;
                r = ((unsigned int)(d - (b << 9)) << 17) | (unsigned int)src_sm[i];
            } else if (i < 2 * NE) {
                int jj = i - NE;
                int d = dst_ms[jj];
                int bs = d >> 7;
                b = NB_M + bs;
                r = ((unsigned int)(d - (bs << 7)) << 17) | (unsigned int)src_ms[jj];
            }
            bk[j] = b; rec[j] = r;
            if (b >= 0) atomicAdd(&lh[b], 1);
        }
        __syncthreads();
        for (int i = t; i < NB; i += 256)
            gb[i] = lh[i] ? atomicAdd(&bcur[i], lh[i]) : 0;
        __syncthreads();
#pragma unroll
        for (int j = 0; j < 16; ++j) {
            int b = bk[j];
            if (b >= 0) {
                int slot = atomicAdd(&lc[b], 1);
                recs[(size_t)b * ECAP + gb[b] + slot] = rec[j];
            }
        }
    } else {
        for (int i = t; i < NB_Q; i += 256) { lh[i] = 0; lc[i] = 0; }
        __syncthreads();
        uint2 rec[16];
        int bk[16];
        int i0 = ((int)blockIdx.x - NBLK_E) * 4096;
#pragma unroll
        for (int j = 0; j < 16; ++j) {
            int i = i0 + j * 256 + t;
            int b = -1; uint2 r = make_uint2(0, 0);
            if (i < NQ) {
                int c = lbl_col[i];
                b = c >> 9;
                r.x = (unsigned int)i;
                r.y = ((unsigned int)(c - (b << 9)) << 15) | (unsigned int)lbl_row[i];
            }
            bk[j] = b; rec[j] = r;
            if (b >= 0) atomicAdd(&lh[b], 1);
        }
        __syncthreads();
        for (int i = t; i < NB_Q; i += 256)
            gb[i] = lh[i] ? atomicAdd(&qbcur[i], lh[i]) : 0;
        __syncthreads();
#pragma unroll
        for (int j = 0; j < 16; ++j) {
            int b = bk[j];
            if (b >= 0) {
                int slot = atomicAdd(&lc[b], 1);
                qrecs[(size_t)b * QCAP + gb[b] + slot] = rec[j];
            }
        }
    }
}

// ---------------------------------------------------------------------------
// Combined per-bucket CSR finalize (unchanged)
// ---------------------------------------------------------------------------
__global__ __launch_bounds__(256) void k_build_all(const unsigned int* __restrict__ recs,
                                                   const int* __restrict__ bcur,
                                                   const uint2* __restrict__ qrecs,
                                                   const int* __restrict__ qbcur,
                                                   int* __restrict__ begd,
                                                   int* __restrict__ degd,
                                                   int* __restrict__ col,
                                                   int* __restrict__ qbeg,
                                                   int* __restrict__ qdeg,
                                                   uint2* __restrict__ qdat) {
    __shared__ int lh[512], lptr[512], lps[256];
    const int t = threadIdx.x;
    if ((int)blockIdx.x < NB) {
        const int b = blockIdx.x;
        const int nd = (b < NB_M) ? min(512, N_MRNA - (b << 9))
                                  : min(128, N_SRNA - ((b - NB_M) << 7));
        const int dst0 = (b < NB_M) ? (b << 9) : N_MRNA + ((b - NB_M) << 7);
        const int base = b * ECAP;
        const int nbe = bcur[b];

        lh[t] = 0; lh[t + 256] = 0;
        __syncthreads();
        for (int e = t; e < nbe; e += 256)
            atomicAdd(&lh[recs[(size_t)base + e] >> 17], 1);
        __syncthreads();

        int a0 = lh[2 * t], a1 = lh[2 * t + 1];
        int ps = a0 + a1;
        lps[t] = ps;
        __syncthreads();
        for (int off = 1; off < 256; off <<= 1) {
            int x = (t >= off) ? lps[t - off] : 0;
            __syncthreads();
            lps[t] += x;
            __syncthreads();
        }
        int ex = lps[t] - ps;
        lptr[2 * t] = ex;
        lptr[2 * t + 1] = ex + a0;
        __syncthreads();

        for (int d = t; d < nd; d += 256) {
            begd[dst0 + d] = base + lptr[d];
            degd[dst0 + d] = lh[d];
        }
        __syncthreads();
        lh[t] = lptr[t]; lh[t + 256] = lptr[t + 256];
        __syncthreads();
        for (int e = t; e < nbe; e += 256) {
            unsigned int r = recs[(size_t)base + e];
            int slot = atomicAdd(&lh[r >> 17], 1);
            col[base + slot] = (int)(r & 0x1FFFFu);
        }
    } else {
        const int b = blockIdx.x - NB;
        const int nd = min(512, N_MRNA - (b << 9));
        const int col0 = b << 9;
        const int base = b * QCAP;
        const int nbe = qbcur[b];

        lh[t] = 0; lh[t + 256] = 0;
        __syncthreads();
        for (int e = t; e < nbe; e += 256)
            atomicAdd(&lh[qrecs[(size_t)base + e].y >> 15], 1);
        __syncthreads();

        int a0 = lh[2 * t], a1 = lh[2 * t + 1];
        int ps = a0 + a1;
        lps[t] = ps;
        __syncthreads();
        for (int off = 1; off < 256; off <<= 1) {
            int x = (t >= off) ? lps[t - off] : 0;
            __syncthreads();
            lps[t] += x;
            __syncthreads();
        }
        int ex = lps[t] - ps;
        lptr[2 * t] = ex;
        lptr[2 * t + 1] = ex + a0;
        __syncthreads();

        for (int d = t; d < nd; d += 256) {
            qbeg[col0 + d] = base + lptr[d];
            qdeg[col0 + d] = lh[d];
        }
        __syncthreads();
        lh[t] = lptr[t]; lh[t + 256] = lptr[t + 256];
        __syncthreads();
        for (int e = t; e < nbe; e += 256) {
            uint2 r = qrecs[(size_t)base + e];
            int slot = atomicAdd(&lh[r.y >> 15], 1);
            qdat[base + slot] = make_uint2(r.y & 0x7FFFu, r.x);   // {row, qidx}
        }
    }
}

// ---------------------------------------------------------------------------
// Merged prep (unchanged)
// ---------------------------------------------------------------------------
__global__ __launch_bounds__(256) void k_prep(
        const float* __restrict__ xs, const float* __restrict__ xm,
        unsigned short* __restrict__ oS, unsigned short* __restrict__ oM,
        const float* __restrict__ Wl0, const float* __restrict__ Wr0, unsigned short* __restrict__ Wt0,
        const float* __restrict__ Wl1, const float* __restrict__ Wr1, unsigned short* __restrict__ Wt1,
        const float* __restrict__ Wl2, const float* __restrict__ Wr2, unsigned short* __restrict__ Wt2,
        const float* __restrict__ Wl3, const float* __restrict__ Wr3, unsigned short* __restrict__ Wt3) {
    if ((int)blockIdx.x < 512) {
        int g = blockIdx.x >> 7;
        const float* Wl; const float* Wr; unsigned short* Wt;
        if (g == 0)      { Wl = Wl0; Wr = Wr0; Wt = Wt0; }
        else if (g == 1) { Wl = Wl1; Wr = Wr1; Wt = Wt1; }
        else if (g == 2) { Wl = Wl2; Wr = Wr2; Wt = Wt2; }
        else             { Wl = Wl3; Wr = Wr3; Wt = Wt3; }
        int tid = (blockIdx.x & 127) * 256 + threadIdx.x;   // 0..32767
        int c = tid & 127, k = tid >> 7;
        float v = (k < 128) ? Wl[k * 128 + c] : Wr[(k - 128) * 128 + c];
        Wt[c * 256 + k] = f2bf(v);
    } else {
        const int nS4 = N_SRNA * FDIM / 4;     // 640000
        const int nT4 = NDST_ALL * FDIM / 4;   // 3840000
        int i = ((int)blockIdx.x - 512) * 256 + threadIdx.x;
        int stride = 2048 * 256;
        for (; i < nT4; i += stride) {
            if (i < nS4) {
                float4 v = ((const float4*)xs)[i];
                unsigned int p0 = (unsigned int)f2bf(v.x) | ((unsigned int)f2bf(v.y) << 16);
                unsigned int p1 = (unsigned int)f2bf(v.z) | ((unsigned int)f2bf(v.w) << 16);
                ((uint2*)oS)[i] = make_uint2(p0, p1);
            } else {
                int j = i - nS4;
                float4 v = ((const float4*)xm)[j];
                unsigned int p0 = (unsigned int)f2bf(v.x) | ((unsigned int)f2bf(v.y) << 16);
                unsigned int p1 = (unsigned int)f2bf(v.z) | ((unsigned int)f2bf(v.w) << 16);
                ((uint2*)oM)[j] = make_uint2(p0, p1);
            }
        }
    }
}

// ---------------------------------------------------------------------------
// Segment mean, row-per-quarter, LOAD-BALANCED waves + index prefetch.
// NDST_ALL == 6 * N_SRNA exactly: wave w handles 4 srna rows when w%6==5,
// else 4 mrna rows — homogeneous waves, srna (deg~50) work spread 1-in-6
// across the grid (no drain tail). Per 8-edge chunk: one coalesced index
// load + shfl broadcast; NEXT chunk's indices are loaded before the current
// accumulate so the index latency hides under 64 FMAs.
// ---------------------------------------------------------------------------
__global__ __launch_bounds__(256) void k_seg_mean2(const unsigned short* __restrict__ srcA,
                                                   const unsigned short* __restrict__ srcB,
                                                   const int* __restrict__ begd,
                                                   const int* __restrict__ degd,
                                                   const int* __restrict__ cols,
                                                   unsigned short* __restrict__ outA,
                                                   unsigned short* __restrict__ outB,
                                                   int nA, int nTot) {
    int wv = (blockIdx.x * 256 + threadIdx.x) >> 6;
    int l = threadIdx.x & 63;
    const int q = l >> 4, lq = l & 15;
    int w6 = wv / 6, wrem = wv - w6 * 6;
    bool is_s = (wrem == 5);
    int r = is_s ? (nA + w6 * 4 + q) : ((w6 * 5 + wrem) * 4 + q);
    if (r >= nTot) return;                                // safety (exact by constants)
    const unsigned short* xs = is_s ? srcB : srcA;
    unsigned short* o = is_s ? (outB + (size_t)(r - nA) * FDIM)
                             : (outA + (size_t)r * FDIM);
    int beg = begd[r];
    int deg = degd[r];

    float acc[8];
#pragma unroll
    for (int k = 0; k < 8; ++k) acc[k] = 0.f;

    if (deg > 0) {
        int ci = cols[beg + min(lq & 7, deg - 1)];
        for (int e0 = 0; e0 < deg; e0 += 8) {
            int rem8 = deg - e0;
            bf16x8 v[8];
#pragma unroll
            for (int i = 0; i < 8; ++i) {
                int s = __shfl(ci, i, 16);                // broadcast within quarter
                v[i] = *(const bf16x8*)(xs + (size_t)s * FDIM + lq * 8);
            }
            int nxt = deg - (e0 + 8);
            if (nxt > 0) ci = cols[beg + e0 + 8 + min(lq & 7, nxt - 1)];
#pragma unroll
            for (int i = 0; i < 8; ++i) {
                if (i < rem8) {
#pragma unroll
                    for (int k = 0; k < 8; ++k) acc[k] += bf2f((unsigned short)v[i][k]);
                }
            }
        }
    }

    float inv = 1.0f / fmaxf((float)deg, 1.0f);
    uint4 pv;
    pv.x = (unsigned int)f2bf(acc[0] * inv) | ((unsigned int)f2bf(acc[1] * inv) << 16);
    pv.y = (unsigned int)f2bf(acc[2] * inv) | ((unsigned int)f2bf(acc[3] * inv) << 16);
    pv.z = (unsigned int)f2bf(acc[4] * inv) | ((unsigned int)f2bf(acc[5] * inv) << 16);
    pv.w = (unsigned int)f2bf(acc[6] * inv) | ((unsigned int)f2bf(acc[7] * inv) << 16);
    ((uint4*)o)[lq] = pv;
}

// ---------------------------------------------------------------------------
// MFMA GEMM, both node types fused in one dispatch (unchanged).
// ---------------------------------------------------------------------------
template <bool RELU>
__global__ __launch_bounds__(256, 2) void k_gemm_mfma2(
        const unsigned short* __restrict__ A0a, const unsigned short* __restrict__ A1a,
        const unsigned short* __restrict__ Wta, const float* __restrict__ biasa,
        unsigned short* __restrict__ outa, int na, int nblka,
        const unsigned short* __restrict__ A0b, const unsigned short* __restrict__ A1b,
        const unsigned short* __restrict__ Wtb, const float* __restrict__ biasb,
        unsigned short* __restrict__ outb, int nb) {
    __shared__ uint4 smem4[4352];
    char* smem = (char*)smem4;

    const unsigned short *A0, *A1, *Wt;
    const float* bias;
    unsigned short* out;
    int n, bid;
    if ((int)blockIdx.x < nblka) {
        A0 = A0a; A1 = A1a; Wt = Wta; bias = biasa; out = outa; n = na; bid = blockIdx.x;
    } else {
        A0 = A0b; A1 = A1b; Wt = Wtb; bias = biasb; out = outb; n = nb; bid = blockIdx.x - nblka;
    }

    const int t = threadIdx.x;
#pragma unroll
    for (int i = 0; i < 16; ++i) {
        int j = i * 256 + t;
        int byteo = j << 4;
        int c = byteo >> 9;
        int off = byteo & 511;
        int swz = off ^ ((c & 7) << 4);
        uint4 v = ((const uint4*)Wt)[j];
        *(uint4*)(smem + c * 512 + swz) = v;
    }
    __syncthreads();

    const int w = t >> 6, l = t & 63;
    const int wr = w >> 1, wc = w & 1;
    const int rowbase = bid * 128 + wr * 64;
    const int colbase = wc * 64;
    const int lr = l & 15;
    const int lk = (l >> 4) * 8;

    f32x4 acc[4][4];
#pragma unroll
    for (int a = 0; a < 4; ++a)
#pragma unroll
        for (int b = 0; b < 4; ++b)
#pragma unroll
            for (int e = 0; e < 4; ++e) acc[a][b][e] = 0.f;

    bf16x8 az;
#pragma unroll
    for (int e = 0; e < 8; ++e) az[e] = 0;

#pragma unroll
    for (int s = 0; s < 8; ++s) {
        const unsigned short* Abuf = (s < 4) ? A0 : A1;
        const int kk = (s & 3) * 32 + lk;
        bf16x8 afr[4];
#pragma unroll
        for (int af = 0; af < 4; ++af) {
            int row = rowbase + af * 16 + lr;
            afr[af] = (row < n) ? *(const bf16x8*)(Abuf + (size_t)row * FDIM + kk) : az;
        }
        bf16x8 bfr[4];
#pragma unroll
        for (int bf = 0; bf < 4; ++bf) {
            int c = colbase + bf * 16 + lr;
            int off = s * 64 + lk * 2;
            int swz = off ^ ((c & 7) << 4);
            bfr[bf] = *(const bf16x8*)(smem + c * 512 + swz);
        }
#pragma unroll
        for (int af = 0; af < 4; ++af)
#pragma unroll
            for (int bf = 0; bf < 4; ++bf)
                acc[af][bf] = __builtin_amdgcn_mfma_f32_16x16x32_bf16(afr[af], bfr[bf],
                                                                      acc[af][bf], 0, 0, 0);
    }

    __syncthreads();
    float* sD = (float*)(smem + w * 17408);

#pragma unroll
    for (int af = 0; af < 4; ++af)
#pragma unroll
        for (int bf = 0; bf < 4; ++bf)
#pragma unroll
            for (int r = 0; r < 4; ++r)
                sD[(af * 16 + (l >> 4) * 4 + r) * 68 + bf * 16 + lr] = acc[af][bf][r];

#pragma unroll
    for (int j = 0; j < 8; ++j) {
        int flat = j * 512 + l * 8;
        int row = flat >> 6;
        int c0 = flat & 63;
        int grow = rowbase + row;
        if (grow >= n) continue;
        float4 v0 = *(float4*)(&sD[row * 68 + c0]);
        float4 v1 = *(float4*)(&sD[row * 68 + c0 + 4]);
        int gc = colbase + c0;
        float4 b0 = *(const float4*)(bias + gc);
        float4 b1 = *(const float4*)(bias + gc + 4);
        float o[8] = {v0.x + b0.x, v0.y + b0.y, v0.z + b0.z, v0.w + b0.w,
                      v1.x + b1.x, v1.y + b1.y, v1.z + b1.z, v1.w + b1.w};
        if (RELU) {
#pragma unroll
            for (int e = 0; e < 8; ++e) o[e] = fmaxf(o[e], 0.f);
        }
        uint4 pv;
        pv.x = (unsigned int)f2bf(o[0]) | ((unsigned int)f2bf(o[1]) << 16);
        pv.y = (unsigned int)f2bf(o[2]) | ((unsigned int)f2bf(o[3]) << 16);
        pv.z = (unsigned int)f2bf(o[4]) | ((unsigned int)f2bf(o[5]) << 16);
        pv.w = (unsigned int)f2bf(o[6]) | ((unsigned int)f2bf(o[7]) << 16);
        *(uint4*)(out + (size_t)grow * FDIM + gc) = pv;
    }
}

// ---------------------------------------------------------------------------
// CSR decoder, quarter-wave (unchanged).
// ---------------------------------------------------------------------------
__global__ __launch_bounds__(256) void k_decoder_csr(const unsigned short* __restrict__ zS,
                                                     const unsigned short* __restrict__ zM,
                                                     const int* __restrict__ qbeg,
                                                     const int* __restrict__ qdeg,
                                                     const uint2* __restrict__ qdat,
                                                     float* __restrict__ out) {
    int c = (blockIdx.x * 256 + threadIdx.x) >> 6;
    int l = threadIdx.x & 63;
    if (c >= N_MRNA) return;
    int cnt = qdeg[c];
    if (cnt == 0) return;
    int beg = qbeg[c];
    const int q = l >> 4, lq = l & 15;

    bf16x8 vm = *(const bf16x8*)(zM + (size_t)c * FDIM + lq * 8);
    float mxf[8];
#pragma unroll
    for (int k = 0; k < 8; ++k) mxf[k] = bf2f((unsigned short)vm[k]);

    for (int e = 0; e < cnt; e += 4) {
        bool valid = (e + q) < cnt;
        int idx = beg + min(e + q, cnt - 1);
        uint2 d = qdat[idx];
        bf16x8 va = *(const bf16x8*)(zS + (size_t)d.x * FDIM + lq * 8);
        float s = 0.f;
#pragma unroll
        for (int k = 0; k < 8; ++k) s += bf2f((unsigned short)va[k]) * mxf[k];
        s += __shfl_xor(s, 1);
        s += __shfl_xor(s, 2);
        s += __shfl_xor(s, 4);
        s += __shfl_xor(s, 8);
        if (valid && lq == 0) out[d.y] = s;
    }
}

// ---------------------------------------------------------------------------
// Launch
// ---------------------------------------------------------------------------
extern "C" void kernel_launch(void* const* d_in, const int* in_sizes, int n_in,
                              void* d_out, int out_size, void* d_ws, size_t ws_size,
                              hipStream_t stream) {
    const float* x_srna = (const float*)d_in[0];
    const float* x_mrna = (const float*)d_in[1];
    const int* src_sm = (const int*)d_in[2];
    const int* dst_sm = (const int*)d_in[3];
    const int* src_ms = (const int*)d_in[4];
    const int* dst_ms = (const int*)d_in[5];
    const int* lbl_row = (const int*)d_in[6];
    const int* lbl_col = (const int*)d_in[7];
    const float* W1l_sm = (const float*)d_in[8];
    const float* W1r_sm = (const float*)d_in[9];
    const float* W1l_ms = (const float*)d_in[10];
    const float* W1r_ms = (const float*)d_in[11];
    const float* W2l_sm = (const float*)d_in[12];
    const float* W2r_sm = (const float*)d_in[13];
    const float* W2l_ms = (const float*)d_in[14];
    const float* W2r_ms = (const float*)d_in[15];
    const float* b1_sm = (const float*)d_in[16];
    const float* b1_ms = (const float*)d_in[17];
    const float* b2_sm = (const float*)d_in[18];
    const float* b2_ms = (const float*)d_in[19];
    float* out = (float*)d_out;

    // Workspace layout (16B aligned)
    char* ws = (char*)d_ws;
    unsigned short* xS_bf   = (unsigned short*)(ws + 0);           //   5,120,000
    unsigned short* xM_bf   = (unsigned short*)(ws + 5120000);     //  25,600,000
    unsigned short* meanM   = (unsigned short*)(ws + 30720000);    //  25,600,000 (becomes zM)
    unsigned short* meanS   = (unsigned short*)(ws + 56320000);    //   5,120,000 (becomes zS)
    unsigned short* hM_bf   = (unsigned short*)(ws + 61440000);    //  25,600,000
    unsigned short* hS_bf   = (unsigned short*)(ws + 87040000);    //   5,120,000
    unsigned short* Wt1sm   = (unsigned short*)(ws + 92160000);    //      65,536
    unsigned short* Wt1ms   = (unsigned short*)(ws + 92225536);    //      65,536
    unsigned short* Wt2sm   = (unsigned short*)(ws + 92291072);    //      65,536
    unsigned short* Wt2ms   = (unsigned short*)(ws + 92356608);    //      65,536
    int* begd               = (int*)(ws + 92422144);               //     480,000
    int* degd               = (int*)(ws + 92902144);               //     480,000
    int* col_all            = (int*)(ws + 93382144);               //  11,567,104 (353*8192*4)
    unsigned int* recs      = (unsigned int*)(ws + 104949248);     //  11,567,104
    uint2* qrecs            = (uint2*)(ws + 116516352);            //   6,422,528 (196*4096*8)
    uint2* qdat             = (uint2*)(ws + 122938880);            //   6,422,528
    int* qbeg               = (int*)(ws + 129361408);              //     400,000
    int* qdeg               = (int*)(ws + 129761408);              //     400,000
    int* bcur               = (int*)(ws + 130161408);              //       1,412 (353 ints)
    int* qbcur              = (int*)(ws + 130162820);              //         784 (196 ints)
    // total ~130.2 MB

    // --- merged dtype prep (wt build + cvt in one dispatch) ---
    k_prep<<<2560, 256, 0, stream>>>(x_srna, x_mrna, xS_bf, xM_bf,
                                     W1l_sm, W1r_sm, Wt1sm,
                                     W1l_ms, W1r_ms, Wt1ms,
                                     W2l_sm, W2r_sm, Wt2sm,
                                     W2l_ms, W2r_ms, Wt2ms);

    // --- zero both cursor arrays with ONE memset (adjacent) ---
    hipMemsetAsync(bcur, 0, (NB + NB_Q) * sizeof(int), stream);

    // --- Combined edge + query binning, then combined finalize ---
    k_scatter_all<<<NBLK_E + NBLK_Q, 256, 0, stream>>>(src_sm, dst_sm, src_ms, dst_ms,
                                                       lbl_row, lbl_col, bcur, qbcur,
                                                       recs, qrecs);
    k_build_all<<<NB + NB_Q, 256, 0, stream>>>(recs, bcur, qrecs, qbcur,
                                               begd, degd, col_all, qbeg, qdeg, qdat);

    const int nblk_m = (N_MRNA + 127) / 128;               // 782
    const int nblk_s = (N_SRNA + 127) / 128;               // 157
    const int segblk = (NDST_ALL + 15) / 16;               // 7500 (4 rows/wave, 4 waves/blk)

    // --- Layer 1 (fused node types) ---
    k_seg_mean2<<<segblk, 256, 0, stream>>>(xS_bf, xM_bf, begd, degd, col_all,
                                            meanM, meanS, N_MRNA, NDST_ALL);
    k_gemm_mfma2<true><<<nblk_m + nblk_s, 256, 0, stream>>>(
        meanM, xM_bf, Wt1sm, b1_sm, hM_bf, N_MRNA, nblk_m,
        meanS, xS_bf, Wt1ms, b1_ms, hS_bf, N_SRNA);

    // --- Layer 2 (z overwrites mean buffers in place) ---
    k_seg_mean2<<<segblk, 256, 0, stream>>>(hS_bf, hM_bf, begd, degd, col_all,
                                            meanM, meanS, N_MRNA, NDST_ALL);
    k_gemm_mfma2<false><<<nblk_m + nblk_s, 256, 0, stream>>>(
        meanM, hM_bf, Wt2sm, b2_sm, meanM, N_MRNA, nblk_m,
        meanS, hS_bf, Wt2ms, b2_ms, meanS, N_SRNA);

    // --- Decoder ---
    k_decoder_csr<<<(N_MRNA + 3) / 4, 256, 0, stream>>>(meanS, meanM, qbeg, qdeg, qdat, out);
}

// Round 12
// 389.183 us; speedup vs baseline: 1.0737x; 1.0737x over previous
//
#include <hip/hip_runtime.h>

// Problem constants (fixed by the reference)
#define N_SRNA  20000
#define N_MRNA  100000
#define FDIM    128
#define NE      1000000
#define NQ      500000
#define NDST_ALL (N_MRNA + N_SRNA)

// Fixed-capacity buckets (no hist/scan prepass); see round-5 sigma analysis.
#define NB_M 196
#define NB_S 157
#define NB   (NB_M + NB_S)            // 353
#define NB_Q 196
#define ECAP 8192
#define QCAP 4096
#define NBLK_E 489                    // (2*NE + 4095) / 4096
#define NBLK_Q 123                    // (NQ + 4095) / 4096

typedef __attribute__((ext_vector_type(8))) short bf16x8;
typedef __attribute__((ext_vector_type(4))) float f32x4;

__device__ __forceinline__ unsigned short f2bf(float f) {
    unsigned int u = __float_as_uint(f);
    unsigned int r = (u + 0x7fffu + ((u >> 16) & 1u)) >> 16;   // RNE
    return (unsigned short)r;
}
__device__ __forceinline__ float bf2f(unsigned short h) {
    return __uint_as_float((unsigned int)h << 16);
}

// ---------------------------------------------------------------------------
// Combined binning scatter (unchanged)
// ---------------------------------------------------------------------------
__global__ __launch_bounds__(256) void k_scatter_all(const int* __restrict__ src_sm,
                                                     const int* __restrict__ dst_sm,
                                                     const int* __restrict__ src_ms,
                                                     const int* __restrict__ dst_ms,
                                                     const int* __restrict__ lbl_row,
                                                     const int* __restrict__ lbl_col,
                                                     int* __restrict__ bcur,
                                                     int* __restrict__ qbcur,
                                                     unsigned int* __restrict__ recs,
                                                     uint2* __restrict__ qrecs) {
    __shared__ int lh[NB], gb[NB], lc[NB];
    int t = threadIdx.x;
    if ((int)blockIdx.x < NBLK_E) {
        for (int i = t; i < NB; i += 256) { lh[i] = 0; lc[i] = 0; }
        __syncthreads();
        unsigned int rec[16];
        int bk[16];
        int i0 = blockIdx.x * 4096;
#pragma unroll
        for (int j = 0; j < 16; ++j) {
            int i = i0 + j * 256 + t;
            int b = -1; unsigned int r = 0;
            if (i < NE) {
                int d = dst_sm[i];
                b = d >> 9;
                r = ((unsigned int)(d - (b << 9)) << 17) | (unsigned int)src_sm[i];
            } else if (i < 2 * NE) {
                int jj = i - NE;
                int d = dst_ms[jj];
                int bs = d >> 7;
                b = NB_M + bs;
                r = ((unsigned int)(d - (bs << 7)) << 17) | (unsigned int)src_ms[jj];
            }
            bk[j] = b; rec[j] = r;
            if (b >= 0) atomicAdd(&lh[b], 1);
        }
        __syncthreads();
        for (int i = t; i < NB; i += 256)
            gb[i] = lh[i] ? atomicAdd(&bcur[i], lh[i]) : 0;
        __syncthreads();
#pragma unroll
        for (int j = 0; j < 16; ++j) {
            int b = bk[j];
            if (b >= 0) {
                int slot = atomicAdd(&lc[b], 1);
                recs[(size_t)b * ECAP + gb[b] + slot] = rec[j];
            }
        }
    } else {
        for (int i = t; i < NB_Q; i += 256) { lh[i] = 0; lc[i] = 0; }
        __syncthreads();
        uint2 rec[16];
        int bk[16];
        int i0 = ((int)blockIdx.x - NBLK_E) * 4096;
#pragma unroll
        for (int j = 0; j < 16; ++j) {
            int i = i0 + j * 256 + t;
            int b = -1; uint2 r = make_uint2(0, 0);
            if (i < NQ) {
                int c = lbl_col[i];
                b = c >> 9;
                r.x = (unsigned int)i;
                r.y = ((unsigned int)(c - (b << 9)) << 15) | (unsigned int)lbl_row[i];
            }
            bk[j] = b; rec[j] = r;
            if (b >= 0) atomicAdd(&lh[b], 1);
        }
        __syncthreads();
        for (int i = t; i < NB_Q; i += 256)
            gb[i] = lh[i] ? atomicAdd(&qbcur[i], lh[i]) : 0;
        __syncthreads();
#pragma unroll
        for (int j = 0; j < 16; ++j) {
            int b = bk[j];
            if (b >= 0) {
                int slot = atomicAdd(&lc[b], 1);
                qrecs[(size_t)b * QCAP + gb[b] + slot] = rec[j];
            }
        }
    }
}

// ---------------------------------------------------------------------------
// Combined per-bucket CSR finalize (unchanged)
// ---------------------------------------------------------------------------
__global__ __launch_bounds__(256) void k_build_all(const unsigned int* __restrict__ recs,
                                                   const int* __restrict__ bcur,
                                                   const uint2* __restrict__ qrecs,
                                                   const int* __restrict__ qbcur,
                                                   int* __restrict__ begd,
                                                   int* __restrict__ degd,
                                                   int* __restrict__ col,
                                                   int* __restrict__ qbeg,
                                                   int* __restrict__ qdeg,
                                                   uint2* __restrict__ qdat) {
    __shared__ int lh[512], lptr[512], lps[256];
    const int t = threadIdx.x;
    if ((int)blockIdx.x < NB) {
        const int b = blockIdx.x;
        const int nd = (b < NB_M) ? min(512, N_MRNA - (b << 9))
                                  : min(128, N_SRNA - ((b - NB_M) << 7));
        const int dst0 = (b < NB_M) ? (b << 9) : N_MRNA + ((b - NB_M) << 7);
        const int base = b * ECAP;
        const int nbe = bcur[b];

        lh[t] = 0; lh[t + 256] = 0;
        __syncthreads();
        for (int e = t; e < nbe; e += 256)
            atomicAdd(&lh[recs[(size_t)base + e] >> 17], 1);
        __syncthreads();

        int a0 = lh[2 * t], a1 = lh[2 * t + 1];
        int ps = a0 + a1;
        lps[t] = ps;
        __syncthreads();
        for (int off = 1; off < 256; off <<= 1) {
            int x = (t >= off) ? lps[t - off] : 0;
            __syncthreads();
            lps[t] += x;
            __syncthreads();
        }
        int ex = lps[t] - ps;
        lptr[2 * t] = ex;
        lptr[2 * t + 1] = ex + a0;
        __syncthreads();

        for (int d = t; d < nd; d += 256) {
            begd[dst0 + d] = base + lptr[d];
            degd[dst0 + d] = lh[d];
        }
        __syncthreads();
        lh[t] = lptr[t]; lh[t + 256] = lptr[t + 256];
        __syncthreads();
        for (int e = t; e < nbe; e += 256) {
            unsigned int r = recs[(size_t)base + e];
            int slot = atomicAdd(&lh[r >> 17], 1);
            col[base + slot] = (int)(r & 0x1FFFFu);
        }
    } else {
        const int b = blockIdx.x - NB;
        const int nd = min(512, N_MRNA - (b << 9));
        const int col0 = b << 9;
        const int base = b * QCAP;
        const int nbe = qbcur[b];

        lh[t] = 0; lh[t + 256] = 0;
        __syncthreads();
        for (int e = t; e < nbe; e += 256)
            atomicAdd(&lh[qrecs[(size_t)base + e].y >> 15], 1);
        __syncthreads();

        int a0 = lh[2 * t], a1 = lh[2 * t + 1];
        int ps = a0 + a1;
        lps[t] = ps;
        __syncthreads();
        for (int off = 1; off < 256; off <<= 1) {
            int x = (t >= off) ? lps[t - off] : 0;
            __syncthreads();
            lps[t] += x;
            __syncthreads();
        }
        int ex = lps[t] - ps;
        lptr[2 * t] = ex;
        lptr[2 * t + 1] = ex + a0;
        __syncthreads();

        for (int d = t; d < nd; d += 256) {
            qbeg[col0 + d] = base + lptr[d];
            qdeg[col0 + d] = lh[d];
        }
        __syncthreads();
        lh[t] = lptr[t]; lh[t + 256] = lptr[t + 256];
        __syncthreads();
        for (int e = t; e < nbe; e += 256) {
            uint2 r = qrecs[(size_t)base + e];
            int slot = atomicAdd(&lh[r.y >> 15], 1);
            qdat[base + slot] = make_uint2(r.y & 0x7FFFu, r.x);   // {row, qidx}
        }
    }
}

// ---------------------------------------------------------------------------
// Merged prep (unchanged)
// ---------------------------------------------------------------------------
__global__ __launch_bounds__(256) void k_prep(
        const float* __restrict__ xs, const float* __restrict__ xm,
        unsigned short* __restrict__ oS, unsigned short* __restrict__ oM,
        const float* __restrict__ Wl0, const float* __restrict__ Wr0, unsigned short* __restrict__ Wt0,
        const float* __restrict__ Wl1, const float* __restrict__ Wr1, unsigned short* __restrict__ Wt1,
        const float* __restrict__ Wl2, const float* __restrict__ Wr2, unsigned short* __restrict__ Wt2,
        const float* __restrict__ Wl3, const float* __restrict__ Wr3, unsigned short* __restrict__ Wt3) {
    if ((int)blockIdx.x < 512) {
        int g = blockIdx.x >> 7;
        const float* Wl; const float* Wr; unsigned short* Wt;
        if (g == 0)      { Wl = Wl0; Wr = Wr0; Wt = Wt0; }
        else if (g == 1) { Wl = Wl1; Wr = Wr1; Wt = Wt1; }
        else if (g == 2) { Wl = Wl2; Wr = Wr2; Wt = Wt2; }
        else             { Wl = Wl3; Wr = Wr3; Wt = Wt3; }
        int tid = (blockIdx.x & 127) * 256 + threadIdx.x;   // 0..32767
        int c = tid & 127, k = tid >> 7;
        float v = (k < 128) ? Wl[k * 128 + c] : Wr[(k - 128) * 128 + c];
        Wt[c * 256 + k] = f2bf(v);
    } else {
        const int nS4 = N_SRNA * FDIM / 4;     // 640000
        const int nT4 = NDST_ALL * FDIM / 4;   // 3840000
        int i = ((int)blockIdx.x - 512) * 256 + threadIdx.x;
        int stride = 2048 * 256;
        for (; i < nT4; i += stride) {
            if (i < nS4) {
                float4 v = ((const float4*)xs)[i];
                unsigned int p0 = (unsigned int)f2bf(v.x) | ((unsigned int)f2bf(v.y) << 16);
                unsigned int p1 = (unsigned int)f2bf(v.z) | ((unsigned int)f2bf(v.w) << 16);
                ((uint2*)oS)[i] = make_uint2(p0, p1);
            } else {
                int j = i - nS4;
                float4 v = ((const float4*)xm)[j];
                unsigned int p0 = (unsigned int)f2bf(v.x) | ((unsigned int)f2bf(v.y) << 16);
                unsigned int p1 = (unsigned int)f2bf(v.z) | ((unsigned int)f2bf(v.w) << 16);
                ((uint2*)oM)[j] = make_uint2(p0, p1);
            }
        }
    }
}

// ---------------------------------------------------------------------------
// Segment mean, hybrid mapping (phase-separated for L2 locality, balanced):
//  - mrna rows (deg~10): waves [0,25000), row-per-quarter, sequential rows.
//    xS table (5MB) stays hot in L2 during this phase.
//  - srna rows (deg~50): waves [25000,45000), ONE ROW PER WAVE; each quarter
//    takes a contiguous ~deg/4 edge slice, cross-quarter shfl_xor combine.
//    20000 waves -> drain phase fully occupied (vs 1250-wave tail before).
// Inner loop (both): one coalesced 8-index load + shfl broadcast + prefetch.
// ---------------------------------------------------------------------------
__global__ __launch_bounds__(256) void k_seg_mean2(const unsigned short* __restrict__ srcA,
                                                   const unsigned short* __restrict__ srcB,
                                                   const int* __restrict__ begd,
                                                   const int* __restrict__ degd,
                                                   const int* __restrict__ cols,
                                                   unsigned short* __restrict__ outA,
                                                   unsigned short* __restrict__ outB,
                                                   int nA, int nTot) {
    int wv = (blockIdx.x * 256 + threadIdx.x) >> 6;
    int l = threadIdx.x & 63;
    const int q = l >> 4, lq = l & 15;
    const int nWm = nA / 4;                               // 25000 mrna waves

    if (wv < nWm) {
        // ---- mrna: row-per-quarter (round-10 proven path) ----
        int r = wv * 4 + q;                               // < nA
        const unsigned short* xs = srcA;
        unsigned short* o = outA + (size_t)r * FDIM;
        int beg = begd[r];
        int deg = degd[r];

        float acc[8];
#pragma unroll
        for (int k = 0; k < 8; ++k) acc[k] = 0.f;

        if (deg > 0) {
            int ci = cols[beg + min(lq & 7, deg - 1)];
            for (int e0 = 0; e0 < deg; e0 += 8) {
                int rem8 = deg - e0;
                bf16x8 v[8];
#pragma unroll
                for (int i = 0; i < 8; ++i) {
                    int s = __shfl(ci, i, 16);
                    v[i] = *(const bf16x8*)(xs + (size_t)s * FDIM + lq * 8);
                }
                int nxt = deg - (e0 + 8);
                if (nxt > 0) ci = cols[beg + e0 + 8 + min(lq & 7, nxt - 1)];
#pragma unroll
                for (int i = 0; i < 8; ++i) {
                    if (i < rem8) {
#pragma unroll
                        for (int k = 0; k < 8; ++k) acc[k] += bf2f((unsigned short)v[i][k]);
                    }
                }
            }
        }
        float inv = 1.0f / fmaxf((float)deg, 1.0f);
        uint4 pv;
        pv.x = (unsigned int)f2bf(acc[0] * inv) | ((unsigned int)f2bf(acc[1] * inv) << 16);
        pv.y = (unsigned int)f2bf(acc[2] * inv) | ((unsigned int)f2bf(acc[3] * inv) << 16);
        pv.z = (unsigned int)f2bf(acc[4] * inv) | ((unsigned int)f2bf(acc[5] * inv) << 16);
        pv.w = (unsigned int)f2bf(acc[6] * inv) | ((unsigned int)f2bf(acc[7] * inv) << 16);
        ((uint4*)o)[lq] = pv;
    } else {
        // ---- srna: row-per-wave, quarter = contiguous edge slice ----
        int r = wv - nWm;                                 // 0..19999
        if (r >= nTot - nA) return;                       // safety
        int gr = nA + r;
        const unsigned short* xs = srcB;
        int beg = begd[gr];
        int deg = degd[gr];

        float acc[8];
#pragma unroll
        for (int k = 0; k < 8; ++k) acc[k] = 0.f;

        int per = (deg + 3) >> 2;
        int e0 = q * per;
        int e1 = min(deg, e0 + per);
        int len = e1 - e0;
        if (len > 0) {
            int ci = cols[beg + e0 + min(lq & 7, len - 1)];
            for (int c0 = 0; c0 < len; c0 += 8) {
                int rem8 = len - c0;
                bf16x8 v[8];
#pragma unroll
                for (int i = 0; i < 8; ++i) {
                    int s = __shfl(ci, i, 16);
                    v[i] = *(const bf16x8*)(xs + (size_t)s * FDIM + lq * 8);
                }
                int nxt = len - (c0 + 8);
                if (nxt > 0) ci = cols[beg + e0 + c0 + 8 + min(lq & 7, nxt - 1)];
#pragma unroll
                for (int i = 0; i < 8; ++i) {
                    if (i < rem8) {
#pragma unroll
                        for (int k = 0; k < 8; ++k) acc[k] += bf2f((unsigned short)v[i][k]);
                    }
                }
            }
        }
        // cross-quarter combine (lanes lq aligned across quarters)
#pragma unroll
        for (int k = 0; k < 8; ++k) {
            acc[k] += __shfl_xor(acc[k], 16);
            acc[k] += __shfl_xor(acc[k], 32);
        }
        if (q == 0) {
            float inv = 1.0f / fmaxf((float)deg, 1.0f);
            uint4 pv;
            pv.x = (unsigned int)f2bf(acc[0] * inv) | ((unsigned int)f2bf(acc[1] * inv) << 16);
            pv.y = (unsigned int)f2bf(acc[2] * inv) | ((unsigned int)f2bf(acc[3] * inv) << 16);
            pv.z = (unsigned int)f2bf(acc[4] * inv) | ((unsigned int)f2bf(acc[5] * inv) << 16);
            pv.w = (unsigned int)f2bf(acc[6] * inv) | ((unsigned int)f2bf(acc[7] * inv) << 16);
            ((uint4*)(outB + (size_t)r * FDIM))[lq] = pv;
        }
    }
}

// ---------------------------------------------------------------------------
// MFMA GEMM, both node types fused in one dispatch (unchanged).
// ---------------------------------------------------------------------------
template <bool RELU>
__global__ __launch_bounds__(256, 2) void k_gemm_mfma2(
        const unsigned short* __restrict__ A0a, const unsigned short* __restrict__ A1a,
        const unsigned short* __restrict__ Wta, const float* __restrict__ biasa,
        unsigned short* __restrict__ outa, int na, int nblka,
        const unsigned short* __restrict__ A0b, const unsigned short* __restrict__ A1b,
        const unsigned short* __restrict__ Wtb, const float* __restrict__ biasb,
        unsigned short* __restrict__ outb, int nb) {
    __shared__ uint4 smem4[4352];
    char* smem = (char*)smem4;

    const unsigned short *A0, *A1, *Wt;
    const float* bias;
    unsigned short* out;
    int n, bid;
    if ((int)blockIdx.x < nblka) {
        A0 = A0a; A1 = A1a; Wt = Wta; bias = biasa; out = outa; n = na; bid = blockIdx.x;
    } else {
        A0 = A0b; A1 = A1b; Wt = Wtb; bias = biasb; out = outb; n = nb; bid = blockIdx.x - nblka;
    }

    const int t = threadIdx.x;
#pragma unroll
    for (int i = 0; i < 16; ++i) {
        int j = i * 256 + t;
        int byteo = j << 4;
        int c = byteo >> 9;
        int off = byteo & 511;
        int swz = off ^ ((c & 7) << 4);
        uint4 v = ((const uint4*)Wt)[j];
        *(uint4*)(smem + c * 512 + swz) = v;
    }
    __syncthreads();

    const int w = t >> 6, l = t & 63;
    const int wr = w >> 1, wc = w & 1;
    const int rowbase = bid * 128 + wr * 64;
    const int colbase = wc * 64;
    const int lr = l & 15;
    const int lk = (l >> 4) * 8;

    f32x4 acc[4][4];
#pragma unroll
    for (int a = 0; a < 4; ++a)
#pragma unroll
        for (int b = 0; b < 4; ++b)
#pragma unroll
            for (int e = 0; e < 4; ++e) acc[a][b][e] = 0.f;

    bf16x8 az;
#pragma unroll
    for (int e = 0; e < 8; ++e) az[e] = 0;

#pragma unroll
    for (int s = 0; s < 8; ++s) {
        const unsigned short* Abuf = (s < 4) ? A0 : A1;
        const int kk = (s & 3) * 32 + lk;
        bf16x8 afr[4];
#pragma unroll
        for (int af = 0; af < 4; ++af) {
            int row = rowbase + af * 16 + lr;
            afr[af] = (row < n) ? *(const bf16x8*)(Abuf + (size_t)row * FDIM + kk) : az;
        }
        bf16x8 bfr[4];
#pragma unroll
        for (int bf = 0; bf < 4; ++bf) {
            int c = colbase + bf * 16 + lr;
            int off = s * 64 + lk * 2;
            int swz = off ^ ((c & 7) << 4);
            bfr[bf] = *(const bf16x8*)(smem + c * 512 + swz);
        }
#pragma unroll
        for (int af = 0; af < 4; ++af)
#pragma unroll
            for (int bf = 0; bf < 4; ++bf)
                acc[af][bf] = __builtin_amdgcn_mfma_f32_16x16x32_bf16(afr[af], bfr[bf],
                                                                      acc[af][bf], 0, 0, 0);
    }

    __syncthreads();
    float* sD = (float*)(smem + w * 17408);

#pragma unroll
    for (int af = 0; af < 4; ++af)
#pragma unroll
        for (int bf = 0; bf < 4; ++bf)
#pragma unroll
            for (int r = 0; r < 4; ++r)
                sD[(af * 16 + (l >> 4) * 4 + r) * 68 + bf * 16 + lr] = acc[af][bf][r];

#pragma unroll
    for (int j = 0; j < 8; ++j) {
        int flat = j * 512 + l * 8;
        int row = flat >> 6;
        int c0 = flat & 63;
        int grow = rowbase + row;
        if (grow >= n) continue;
        float4 v0 = *(float4*)(&sD[row * 68 + c0]);
        float4 v1 = *(float4*)(&sD[row * 68 + c0 + 4]);
        int gc = colbase + c0;
        float4 b0 = *(const float4*)(bias + gc);
        float4 b1 = *(const float4*)(bias + gc + 4);
        float o[8] = {v0.x + b0.x, v0.y + b0.y, v0.z + b0.z, v0.w + b0.w,
                      v1.x + b1.x, v1.y + b1.y, v1.z + b1.z, v1.w + b1.w};
        if (RELU) {
#pragma unroll
            for (int e = 0; e < 8; ++e) o[e] = fmaxf(o[e], 0.f);
        }
        uint4 pv;
        pv.x = (unsigned int)f2bf(o[0]) | ((unsigned int)f2bf(o[1]) << 16);
        pv.y = (unsigned int)f2bf(o[2]) | ((unsigned int)f2bf(o[3]) << 16);
        pv.z = (unsigned int)f2bf(o[4]) | ((unsigned int)f2bf(o[5]) << 16);
        pv.w = (unsigned int)f2bf(o[6]) | ((unsigned int)f2bf(o[7]) << 16);
        *(uint4*)(out + (size_t)grow * FDIM + gc) = pv;
    }
}

// ---------------------------------------------------------------------------
// CSR decoder, quarter-wave (unchanged).
// ---------------------------------------------------------------------------
__global__ __launch_bounds__(256) void k_decoder_csr(const unsigned short* __restrict__ zS,
                                                     const unsigned short* __restrict__ zM,
                                                     const int* __restrict__ qbeg,
                                                     const int* __restrict__ qdeg,
                                                     const uint2* __restrict__ qdat,
                                                     float* __restrict__ out) {
    int c = (blockIdx.x * 256 + threadIdx.x) >> 6;
    int l = threadIdx.x & 63;
    if (c >= N_MRNA) return;
    int cnt = qdeg[c];
    if (cnt == 0) return;
    int beg = qbeg[c];
    const int q = l >> 4, lq = l & 15;

    bf16x8 vm = *(const bf16x8*)(zM + (size_t)c * FDIM + lq * 8);
    float mxf[8];
#pragma unroll
    for (int k = 0; k < 8; ++k) mxf[k] = bf2f((unsigned short)vm[k]);

    for (int e = 0; e < cnt; e += 4) {
        bool valid = (e + q) < cnt;
        int idx = beg + min(e + q, cnt - 1);
        uint2 d = qdat[idx];
        bf16x8 va = *(const bf16x8*)(zS + (size_t)d.x * FDIM + lq * 8);
        float s = 0.f;
#pragma unroll
        for (int k = 0; k < 8; ++k) s += bf2f((unsigned short)va[k]) * mxf[k];
        s += __shfl_xor(s, 1);
        s += __shfl_xor(s, 2);
        s += __shfl_xor(s, 4);
        s += __shfl_xor(s, 8);
        if (valid && lq == 0) out[d.y] = s;
    }
}

// ---------------------------------------------------------------------------
// Launch
// ---------------------------------------------------------------------------
extern "C" void kernel_launch(void* const* d_in, const int* in_sizes, int n_in,
                              void* d_out, int out_size, void* d_ws, size_t ws_size,
                              hipStream_t stream) {
    const float* x_srna = (const float*)d_in[0];
    const float* x_mrna = (const float*)d_in[1];
    const int* src_sm = (const int*)d_in[2];
    const int* dst_sm = (const int*)d_in[3];
    const int* src_ms = (const int*)d_in[4];
    const int* dst_ms = (const int*)d_in[5];
    const int* lbl_row = (const int*)d_in[6];
    const int* lbl_col = (const int*)d_in[7];
    const float* W1l_sm = (const float*)d_in[8];
    const float* W1r_sm = (const float*)d_in[9];
    const float* W1l_ms = (const float*)d_in[10];
    const float* W1r_ms = (const float*)d_in[11];
    const float* W2l_sm = (const float*)d_in[12];
    const float* W2r_sm = (const float*)d_in[13];
    const float* W2l_ms = (const float*)d_in[14];
    const float* W2r_ms = (const float*)d_in[15];
    const float* b1_sm = (const float*)d_in[16];
    const float* b1_ms = (const float*)d_in[17];
    const float* b2_sm = (const float*)d_in[18];
    const float* b2_ms = (const float*)d_in[19];
    float* out = (float*)d_out;

    // Workspace layout (16B aligned)
    char* ws = (char*)d_ws;
    unsigned short* xS_bf   = (unsigned short*)(ws + 0);           //   5,120,000
    unsigned short* xM_bf   = (unsigned short*)(ws + 5120000);     //  25,600,000
    unsigned short* meanM   = (unsigned short*)(ws + 30720000);    //  25,600,000 (becomes zM)
    unsigned short* meanS   = (unsigned short*)(ws + 56320000);    //   5,120,000 (becomes zS)
    unsigned short* hM_bf   = (unsigned short*)(ws + 61440000);    //  25,600,000
    unsigned short* hS_bf   = (unsigned short*)(ws + 87040000);    //   5,120,000
    unsigned short* Wt1sm   = (unsigned short*)(ws + 92160000);    //      65,536
    unsigned short* Wt1ms   = (unsigned short*)(ws + 92225536);    //      65,536
    unsigned short* Wt2sm   = (unsigned short*)(ws + 92291072);    //      65,536
    unsigned short* Wt2ms   = (unsigned short*)(ws + 92356608);    //      65,536
    int* begd               = (int*)(ws + 92422144);               //     480,000
    int* degd               = (int*)(ws + 92902144);               //     480,000
    int* col_all            = (int*)(ws + 93382144);               //  11,567,104 (353*8192*4)
    unsigned int* recs      = (unsigned int*)(ws + 104949248);     //  11,567,104
    uint2* qrecs            = (uint2*)(ws + 116516352);            //   6,422,528 (196*4096*8)
    uint2* qdat             = (uint2*)(ws + 122938880);            //   6,422,528
    int* qbeg               = (int*)(ws + 129361408);              //     400,000
    int* qdeg               = (int*)(ws + 129761408);              //     400,000
    int* bcur               = (int*)(ws + 130161408);              //       1,412 (353 ints)
    int* qbcur              = (int*)(ws + 130162820);              //         784 (196 ints)
    // total ~130.2 MB

    // --- merged dtype prep (wt build + cvt in one dispatch) ---
    k_prep<<<2560, 256, 0, stream>>>(x_srna, x_mrna, xS_bf, xM_bf,
                                     W1l_sm, W1r_sm, Wt1sm,
                                     W1l_ms, W1r_ms, Wt1ms,
                                     W2l_sm, W2r_sm, Wt2sm,
                                     W2l_ms, W2r_ms, Wt2ms);

    // --- zero both cursor arrays with ONE memset (adjacent) ---
    hipMemsetAsync(bcur, 0, (NB + NB_Q) * sizeof(int), stream);

    // --- Combined edge + query binning, then combined finalize ---
    k_scatter_all<<<NBLK_E + NBLK_Q, 256, 0, stream>>>(src_sm, dst_sm, src_ms, dst_ms,
                                                       lbl_row, lbl_col, bcur, qbcur,
                                                       recs, qrecs);
    k_build_all<<<NB + NB_Q, 256, 0, stream>>>(recs, bcur, qrecs, qbcur,
                                               begd, degd, col_all, qbeg, qdeg, qdat);

    const int nblk_m = (N_MRNA + 127) / 128;               // 782
    const int nblk_s = (N_SRNA + 127) / 128;               // 157
    // waves: 25000 mrna (4 rows/quarter-wave) + 20000 srna (1 row/wave)
    const int segblk = (N_MRNA / 4 + N_SRNA + 3) / 4;      // 11250 blocks (4 waves each)

    // --- Layer 1 (fused node types) ---
    k_seg_mean2<<<segblk, 256, 0, stream>>>(xS_bf, xM_bf, begd, degd, col_all,
                                            meanM, meanS, N_MRNA, NDST_ALL);
    k_gemm_mfma2<true><<<nblk_m + nblk_s, 256, 0, stream>>>(
        meanM, xM_bf, Wt1sm, b1_sm, hM_bf, N_MRNA, nblk_m,
        meanS, xS_bf, Wt1ms, b1_ms, hS_bf, N_SRNA);

    // --- Layer 2 (z overwrites mean buffers in place) ---
    k_seg_mean2<<<segblk, 256, 0, stream>>>(hS_bf, hM_bf, begd, degd, col_all,
                                            meanM, meanS, N_MRNA, NDST_ALL);
    k_gemm_mfma2<false><<<nblk_m + nblk_s, 256, 0, stream>>>(
        meanM, hM_bf, Wt2sm, b2_sm, meanM, N_MRNA, nblk_m,
        meanS, hS_bf, Wt2ms, b2_ms, meanS, N_SRNA);

    // --- Decoder ---
    k_decoder_csr<<<(N_MRNA + 3) / 4, 256, 0, stream>>>(meanS, meanM, qbeg, qdeg, qdat, out);
}

// Round 13
// 382.658 us; speedup vs baseline: 1.0920x; 1.0171x over previous
//
#include <hip/hip_runtime.h>

// Problem constants (fixed by the reference)
#define N_SRNA  20000
#define N_MRNA  100000
#define FDIM    128
#define NE      1000000
#define NQ      500000
#define NDST_ALL (N_MRNA + N_SRNA)

// Fixed-capacity buckets (no hist/scan prepass); see round-5 sigma analysis.
#define NB_M 196
#define NB_S 157
#define NB   (NB_M + NB_S)            // 353
#define NB_Q 196
#define ECAP 8192
#define QCAP 4096
#define NBLK_E 489                    // (2*NE + 4095) / 4096
#define NBLK_Q 123                    // (NQ + 4095) / 4096

typedef __attribute__((ext_vector_type(8))) short bf16x8;
typedef __attribute__((ext_vector_type(4))) float f32x4;

__device__ __forceinline__ unsigned short f2bf(float f) {
    unsigned int u = __float_as_uint(f);
    unsigned int r = (u + 0x7fffu + ((u >> 16) & 1u)) >> 16;   // RNE
    return (unsigned short)r;
}
__device__ __forceinline__ float bf2f(unsigned short h) {
    return __uint_as_float((unsigned int)h << 16);
}

// ---------------------------------------------------------------------------
// Combined binning scatter (unchanged)
// ---------------------------------------------------------------------------
__global__ __launch_bounds__(256) void k_scatter_all(const int* __restrict__ src_sm,
                                                     const int* __restrict__ dst_sm,
                                                     const int* __restrict__ src_ms,
                                                     const int* __restrict__ dst_ms,
                                                     const int* __restrict__ lbl_row,
                                                     const int* __restrict__ lbl_col,
                                                     int* __restrict__ bcur,
                                                     int* __restrict__ qbcur,
                                                     unsigned int* __restrict__ recs,
                                                     uint2* __restrict__ qrecs) {
    __shared__ int lh[NB], gb[NB], lc[NB];
    int t = threadIdx.x;
    if ((int)blockIdx.x < NBLK_E) {
        for (int i = t; i < NB; i += 256) { lh[i] = 0; lc[i] = 0; }
        __syncthreads();
        unsigned int rec[16];
        int bk[16];
        int i0 = blockIdx.x * 4096;
#pragma unroll
        for (int j = 0; j < 16; ++j) {
            int i = i0 + j * 256 + t;
            int b = -1; unsigned int r = 0;
            if (i < NE) {
                int d = dst_sm[i];
                b = d >> 9;
                r = ((unsigned int)(d - (b << 9)) << 17) | (unsigned int)src_sm[i];
            } else if (i < 2 * NE) {
                int jj = i - NE;
                int d = dst_ms[jj];
                int bs = d >> 7;
                b = NB_M + bs;
                r = ((unsigned int)(d - (bs << 7)) << 17) | (unsigned int)src_ms[jj];
            }
            bk[j] = b; rec[j] = r;
            if (b >= 0) atomicAdd(&lh[b], 1);
        }
        __syncthreads();
        for (int i = t; i < NB; i += 256)
            gb[i] = lh[i] ? atomicAdd(&bcur[i], lh[i]) : 0;
        __syncthreads();
#pragma unroll
        for (int j = 0; j < 16; ++j) {
            int b = bk[j];
            if (b >= 0) {
                int slot = atomicAdd(&lc[b], 1);
                recs[(size_t)b * ECAP + gb[b] + slot] = rec[j];
            }
        }
    } else {
        for (int i = t; i < NB_Q; i += 256) { lh[i] = 0; lc[i] = 0; }
        __syncthreads();
        uint2 rec[16];
        int bk[16];
        int i0 = ((int)blockIdx.x - NBLK_E) * 4096;
#pragma unroll
        for (int j = 0; j < 16; ++j) {
            int i = i0 + j * 256 + t;
            int b = -1; uint2 r = make_uint2(0, 0);
            if (i < NQ) {
                int c = lbl_col[i];
                b = c >> 9;
                r.x = (unsigned int)i;
                r.y = ((unsigned int)(c - (b << 9)) << 15) | (unsigned int)lbl_row[i];
            }
            bk[j] = b; rec[j] = r;
            if (b >= 0) atomicAdd(&lh[b], 1);
        }
        __syncthreads();
        for (int i = t; i < NB_Q; i += 256)
            gb[i] = lh[i] ? atomicAdd(&qbcur[i], lh[i]) : 0;
        __syncthreads();
#pragma unroll
        for (int j = 0; j < 16; ++j) {
            int b = bk[j];
            if (b >= 0) {
                int slot = atomicAdd(&lc[b], 1);
                qrecs[(size_t)b * QCAP + gb[b] + slot] = rec[j];
            }
        }
    }
}

// ---------------------------------------------------------------------------
// Combined per-bucket CSR finalize (unchanged)
// ---------------------------------------------------------------------------
__global__ __launch_bounds__(256) void k_build_all(const unsigned int* __restrict__ recs,
                                                   const int* __restrict__ bcur,
                                                   const uint2* __restrict__ qrecs,
                                                   const int* __restrict__ qbcur,
                                                   int* __restrict__ begd,
                                                   int* __restrict__ degd,
                                                   int* __restrict__ col,
                                                   int* __restrict__ qbeg,
                                                   int* __restrict__ qdeg,
                                                   uint2* __restrict__ qdat) {
    __shared__ int lh[512], lptr[512], lps[256];
    const int t = threadIdx.x;
    if ((int)blockIdx.x < NB) {
        const int b = blockIdx.x;
        const int nd = (b < NB_M) ? min(512, N_MRNA - (b << 9))
                                  : min(128, N_SRNA - ((b - NB_M) << 7));
        const int dst0 = (b < NB_M) ? (b << 9) : N_MRNA + ((b - NB_M) << 7);
        const int base = b * ECAP;
        const int nbe = bcur[b];

        lh[t] = 0; lh[t + 256] = 0;
        __syncthreads();
        for (int e = t; e < nbe; e += 256)
            atomicAdd(&lh[recs[(size_t)base + e] >> 17], 1);
        __syncthreads();

        int a0 = lh[2 * t], a1 = lh[2 * t + 1];
        int ps = a0 + a1;
        lps[t] = ps;
        __syncthreads();
        for (int off = 1; off < 256; off <<= 1) {
            int x = (t >= off) ? lps[t - off] : 0;
            __syncthreads();
            lps[t] += x;
            __syncthreads();
        }
        int ex = lps[t] - ps;
        lptr[2 * t] = ex;
        lptr[2 * t + 1] = ex + a0;
        __syncthreads();

        for (int d = t; d < nd; d += 256) {
            begd[dst0 + d] = base + lptr[d];
            degd[dst0 + d] = lh[d];
        }
        __syncthreads();
        lh[t] = lptr[t]; lh[t + 256] = lptr[t + 256];
        __syncthreads();
        for (int e = t; e < nbe; e += 256) {
            unsigned int r = recs[(size_t)base + e];
            int slot = atomicAdd(&lh[r >> 17], 1);
            col[base + slot] = (int)(r & 0x1FFFFu);
        }
    } else {
        const int b = blockIdx.x - NB;
        const int nd = min(512, N_MRNA - (b << 9));
        const int col0 = b << 9;
        const int base = b * QCAP;
        const int nbe = qbcur[b];

        lh[t] = 0; lh[t + 256] = 0;
        __syncthreads();
        for (int e = t; e < nbe; e += 256)
            atomicAdd(&lh[qrecs[(size_t)base + e].y >> 15], 1);
        __syncthreads();

        int a0 = lh[2 * t], a1 = lh[2 * t + 1];
        int ps = a0 + a1;
        lps[t] = ps;
        __syncthreads();
        for (int off = 1; off < 256; off <<= 1) {
            int x = (t >= off) ? lps[t - off] : 0;
            __syncthreads();
            lps[t] += x;
            __syncthreads();
        }
        int ex = lps[t] - ps;
        lptr[2 * t] = ex;
        lptr[2 * t + 1] = ex + a0;
        __syncthreads();

        for (int d = t; d < nd; d += 256) {
            qbeg[col0 + d] = base + lptr[d];
            qdeg[col0 + d] = lh[d];
        }
        __syncthreads();
        lh[t] = lptr[t]; lh[t + 256] = lptr[t + 256];
        __syncthreads();
        for (int e = t; e < nbe; e += 256) {
            uint2 r = qrecs[(size_t)base + e];
            int slot = atomicAdd(&lh[r.y >> 15], 1);
            qdat[base + slot] = make_uint2(r.y & 0x7FFFu, r.x);   // {row, qidx}
        }
    }
}

// ---------------------------------------------------------------------------
// Merged prep (unchanged)
// ---------------------------------------------------------------------------
__global__ __launch_bounds__(256) void k_prep(
        const float* __restrict__ xs, const float* __restrict__ xm,
        unsigned short* __restrict__ oS, unsigned short* __restrict__ oM,
        const float* __restrict__ Wl0, const float* __restrict__ Wr0, unsigned short* __restrict__ Wt0,
        const float* __restrict__ Wl1, const float* __restrict__ Wr1, unsigned short* __restrict__ Wt1,
        const float* __restrict__ Wl2, const float* __restrict__ Wr2, unsigned short* __restrict__ Wt2,
        const float* __restrict__ Wl3, const float* __restrict__ Wr3, unsigned short* __restrict__ Wt3) {
    if ((int)blockIdx.x < 512) {
        int g = blockIdx.x >> 7;
        const float* Wl; const float* Wr; unsigned short* Wt;
        if (g == 0)      { Wl = Wl0; Wr = Wr0; Wt = Wt0; }
        else if (g == 1) { Wl = Wl1; Wr = Wr1; Wt = Wt1; }
        else if (g == 2) { Wl = Wl2; Wr = Wr2; Wt = Wt2; }
        else             { Wl = Wl3; Wr = Wr3; Wt = Wt3; }
        int tid = (blockIdx.x & 127) * 256 + threadIdx.x;   // 0..32767
        int c = tid & 127, k = tid >> 7;
        float v = (k < 128) ? Wl[k * 128 + c] : Wr[(k - 128) * 128 + c];
        Wt[c * 256 + k] = f2bf(v);
    } else {
        const int nS4 = N_SRNA * FDIM / 4;     // 640000
        const int nT4 = NDST_ALL * FDIM / 4;   // 3840000
        int i = ((int)blockIdx.x - 512) * 256 + threadIdx.x;
        int stride = 2048 * 256;
        for (; i < nT4; i += stride) {
            if (i < nS4) {
                float4 v = ((const float4*)xs)[i];
                unsigned int p0 = (unsigned int)f2bf(v.x) | ((unsigned int)f2bf(v.y) << 16);
                unsigned int p1 = (unsigned int)f2bf(v.z) | ((unsigned int)f2bf(v.w) << 16);
                ((uint2*)oS)[i] = make_uint2(p0, p1);
            } else {
                int j = i - nS4;
                float4 v = ((const float4*)xm)[j];
                unsigned int p0 = (unsigned int)f2bf(v.x) | ((unsigned int)f2bf(v.y) << 16);
                unsigned int p1 = (unsigned int)f2bf(v.z) | ((unsigned int)f2bf(v.w) << 16);
                ((uint2*)oM)[j] = make_uint2(p0, p1);
            }
        }
    }
}

// ---------------------------------------------------------------------------
// Segment mean, hybrid mapping + 2-rows-per-quarter mrna phase:
//  - mrna rows (deg~10): waves [0,12500), TWO rows per quarter processed in
//    lockstep -> 16 independent row-gathers in flight per quarter. Sequential
//    row order preserved per row (same fp32 sum order). xS hot in L2.
//  - srna rows (deg~50): waves [12500,32500), one row per wave, quarter =
//    contiguous edge slice, cross-quarter shfl_xor combine (round-12 path).
// ---------------------------------------------------------------------------
__global__ __launch_bounds__(256) void k_seg_mean2(const unsigned short* __restrict__ srcA,
                                                   const unsigned short* __restrict__ srcB,
                                                   const int* __restrict__ begd,
                                                   const int* __restrict__ degd,
                                                   const int* __restrict__ cols,
                                                   unsigned short* __restrict__ outA,
                                                   unsigned short* __restrict__ outB,
                                                   int nA, int nTot) {
    int wv = (blockIdx.x * 256 + threadIdx.x) >> 6;
    int l = threadIdx.x & 63;
    const int q = l >> 4, lq = l & 15;
    const int nWm = nA / 8;                               // 12500 mrna waves

    if (wv < nWm) {
        // ---- mrna: 2 rows per quarter, lockstep chunk loops ----
        int r0 = wv * 8 + q * 2;                          // rows r0, r0+1 (< nA)
        int beg0 = begd[r0],     deg0 = degd[r0];
        int beg1 = begd[r0 + 1], deg1 = degd[r0 + 1];

        float acc0[8], acc1[8];
#pragma unroll
        for (int k = 0; k < 8; ++k) { acc0[k] = 0.f; acc1[k] = 0.f; }

        int ci0 = (deg0 > 0) ? cols[beg0 + min(lq & 7, deg0 - 1)] : 0;
        int ci1 = (deg1 > 0) ? cols[beg1 + min(lq & 7, deg1 - 1)] : 0;
        int dmax = max(deg0, deg1);
        for (int e0 = 0; e0 < dmax; e0 += 8) {
            int rem0 = deg0 - e0, rem1 = deg1 - e0;
            bf16x8 v0[8], v1[8];
#pragma unroll
            for (int i = 0; i < 8; ++i) {
                int s0 = __shfl(ci0, i, 16);
                v0[i] = *(const bf16x8*)(srcA + (size_t)s0 * FDIM + lq * 8);
            }
#pragma unroll
            for (int i = 0; i < 8; ++i) {
                int s1 = __shfl(ci1, i, 16);
                v1[i] = *(const bf16x8*)(srcA + (size_t)s1 * FDIM + lq * 8);
            }
            int n0 = deg0 - (e0 + 8);
            if (n0 > 0) ci0 = cols[beg0 + e0 + 8 + min(lq & 7, n0 - 1)];
            int n1 = deg1 - (e0 + 8);
            if (n1 > 0) ci1 = cols[beg1 + e0 + 8 + min(lq & 7, n1 - 1)];
#pragma unroll
            for (int i = 0; i < 8; ++i) {
                if (i < rem0) {
#pragma unroll
                    for (int k = 0; k < 8; ++k) acc0[k] += bf2f((unsigned short)v0[i][k]);
                }
            }
#pragma unroll
            for (int i = 0; i < 8; ++i) {
                if (i < rem1) {
#pragma unroll
                    for (int k = 0; k < 8; ++k) acc1[k] += bf2f((unsigned short)v1[i][k]);
                }
            }
        }
        float inv0 = 1.0f / fmaxf((float)deg0, 1.0f);
        float inv1 = 1.0f / fmaxf((float)deg1, 1.0f);
        uint4 p0, p1;
        p0.x = (unsigned int)f2bf(acc0[0] * inv0) | ((unsigned int)f2bf(acc0[1] * inv0) << 16);
        p0.y = (unsigned int)f2bf(acc0[2] * inv0) | ((unsigned int)f2bf(acc0[3] * inv0) << 16);
        p0.z = (unsigned int)f2bf(acc0[4] * inv0) | ((unsigned int)f2bf(acc0[5] * inv0) << 16);
        p0.w = (unsigned int)f2bf(acc0[6] * inv0) | ((unsigned int)f2bf(acc0[7] * inv0) << 16);
        p1.x = (unsigned int)f2bf(acc1[0] * inv1) | ((unsigned int)f2bf(acc1[1] * inv1) << 16);
        p1.y = (unsigned int)f2bf(acc1[2] * inv1) | ((unsigned int)f2bf(acc1[3] * inv1) << 16);
        p1.z = (unsigned int)f2bf(acc1[4] * inv1) | ((unsigned int)f2bf(acc1[5] * inv1) << 16);
        p1.w = (unsigned int)f2bf(acc1[6] * inv1) | ((unsigned int)f2bf(acc1[7] * inv1) << 16);
        ((uint4*)(outA + (size_t)r0 * FDIM))[lq] = p0;
        ((uint4*)(outA + (size_t)(r0 + 1) * FDIM))[lq] = p1;
    } else {
        // ---- srna: row-per-wave, quarter = contiguous edge slice ----
        int r = wv - nWm;                                 // 0..19999
        if (r >= nTot - nA) return;                       // safety
        int gr = nA + r;
        const unsigned short* xs = srcB;
        int beg = begd[gr];
        int deg = degd[gr];

        float acc[8];
#pragma unroll
        for (int k = 0; k < 8; ++k) acc[k] = 0.f;

        int per = (deg + 3) >> 2;
        int e0 = q * per;
        int e1 = min(deg, e0 + per);
        int len = e1 - e0;
        if (len > 0) {
            int ci = cols[beg + e0 + min(lq & 7, len - 1)];
            for (int c0 = 0; c0 < len; c0 += 8) {
                int rem8 = len - c0;
                bf16x8 v[8];
#pragma unroll
                for (int i = 0; i < 8; ++i) {
                    int s = __shfl(ci, i, 16);
                    v[i] = *(const bf16x8*)(xs + (size_t)s * FDIM + lq * 8);
                }
                int nxt = len - (c0 + 8);
                if (nxt > 0) ci = cols[beg + e0 + c0 + 8 + min(lq & 7, nxt - 1)];
#pragma unroll
                for (int i = 0; i < 8; ++i) {
                    if (i < rem8) {
#pragma unroll
                        for (int k = 0; k < 8; ++k) acc[k] += bf2f((unsigned short)v[i][k]);
                    }
                }
            }
        }
        // cross-quarter combine (lanes lq aligned across quarters)
#pragma unroll
        for (int k = 0; k < 8; ++k) {
            acc[k] += __shfl_xor(acc[k], 16);
            acc[k] += __shfl_xor(acc[k], 32);
        }
        if (q == 0) {
            float inv = 1.0f / fmaxf((float)deg, 1.0f);
            uint4 pv;
            pv.x = (unsigned int)f2bf(acc[0] * inv) | ((unsigned int)f2bf(acc[1] * inv) << 16);
            pv.y = (unsigned int)f2bf(acc[2] * inv) | ((unsigned int)f2bf(acc[3] * inv) << 16);
            pv.z = (unsigned int)f2bf(acc[4] * inv) | ((unsigned int)f2bf(acc[5] * inv) << 16);
            pv.w = (unsigned int)f2bf(acc[6] * inv) | ((unsigned int)f2bf(acc[7] * inv) << 16);
            ((uint4*)(outB + (size_t)r * FDIM))[lq] = pv;
        }
    }
}

// ---------------------------------------------------------------------------
// MFMA GEMM, both node types fused in one dispatch (unchanged).
// ---------------------------------------------------------------------------
template <bool RELU>
__global__ __launch_bounds__(256, 2) void k_gemm_mfma2(
        const unsigned short* __restrict__ A0a, const unsigned short* __restrict__ A1a,
        const unsigned short* __restrict__ Wta, const float* __restrict__ biasa,
        unsigned short* __restrict__ outa, int na, int nblka,
        const unsigned short* __restrict__ A0b, const unsigned short* __restrict__ A1b,
        const unsigned short* __restrict__ Wtb, const float* __restrict__ biasb,
        unsigned short* __restrict__ outb, int nb) {
    __shared__ uint4 smem4[4352];
    char* smem = (char*)smem4;

    const unsigned short *A0, *A1, *Wt;
    const float* bias;
    unsigned short* out;
    int n, bid;
    if ((int)blockIdx.x < nblka) {
        A0 = A0a; A1 = A1a; Wt = Wta; bias = biasa; out = outa; n = na; bid = blockIdx.x;
    } else {
        A0 = A0b; A1 = A1b; Wt = Wtb; bias = biasb; out = outb; n = nb; bid = blockIdx.x - nblka;
    }

    const int t = threadIdx.x;
#pragma unroll
    for (int i = 0; i < 16; ++i) {
        int j = i * 256 + t;
        int byteo = j << 4;
        int c = byteo >> 9;
        int off = byteo & 511;
        int swz = off ^ ((c & 7) << 4);
        uint4 v = ((const uint4*)Wt)[j];
        *(uint4*)(smem + c * 512 + swz) = v;
    }
    __syncthreads();

    const int w = t >> 6, l = t & 63;
    const int wr = w >> 1, wc = w & 1;
    const int rowbase = bid * 128 + wr * 64;
    const int colbase = wc * 64;
    const int lr = l & 15;
    const int lk = (l >> 4) * 8;

    f32x4 acc[4][4];
#pragma unroll
    for (int a = 0; a < 4; ++a)
#pragma unroll
        for (int b = 0; b < 4; ++b)
#pragma unroll
            for (int e = 0; e < 4; ++e) acc[a][b][e] = 0.f;

    bf16x8 az;
#pragma unroll
    for (int e = 0; e < 8; ++e) az[e] = 0;

#pragma unroll
    for (int s = 0; s < 8; ++s) {
        const unsigned short* Abuf = (s < 4) ? A0 : A1;
        const int kk = (s & 3) * 32 + lk;
        bf16x8 afr[4];
#pragma unroll
        for (int af = 0; af < 4; ++af) {
            int row = rowbase + af * 16 + lr;
            afr[af] = (row < n) ? *(const bf16x8*)(Abuf + (size_t)row * FDIM + kk) : az;
        }
        bf16x8 bfr[4];
#pragma unroll
        for (int bf = 0; bf < 4; ++bf) {
            int c = colbase + bf * 16 + lr;
            int off = s * 64 + lk * 2;
            int swz = off ^ ((c & 7) << 4);
            bfr[bf] = *(const bf16x8*)(smem + c * 512 + swz);
        }
#pragma unroll
        for (int af = 0; af < 4; ++af)
#pragma unroll
            for (int bf = 0; bf < 4; ++bf)
                acc[af][bf] = __builtin_amdgcn_mfma_f32_16x16x32_bf16(afr[af], bfr[bf],
                                                                      acc[af][bf], 0, 0, 0);
    }

    __syncthreads();
    float* sD = (float*)(smem + w * 17408);

#pragma unroll
    for (int af = 0; af < 4; ++af)
#pragma unroll
        for (int bf = 0; bf < 4; ++bf)
#pragma unroll
            for (int r = 0; r < 4; ++r)
                sD[(af * 16 + (l >> 4) * 4 + r) * 68 + bf * 16 + lr] = acc[af][bf][r];

#pragma unroll
    for (int j = 0; j < 8; ++j) {
        int flat = j * 512 + l * 8;
        int row = flat >> 6;
        int c0 = flat & 63;
        int grow = rowbase + row;
        if (grow >= n) continue;
        float4 v0 = *(float4*)(&sD[row * 68 + c0]);
        float4 v1 = *(float4*)(&sD[row * 68 + c0 + 4]);
        int gc = colbase + c0;
        float4 b0 = *(const float4*)(bias + gc);
        float4 b1 = *(const float4*)(bias + gc + 4);
        float o[8] = {v0.x + b0.x, v0.y + b0.y, v0.z + b0.z, v0.w + b0.w,
                      v1.x + b1.x, v1.y + b1.y, v1.z + b1.z, v1.w + b1.w};
        if (RELU) {
#pragma unroll
            for (int e = 0; e < 8; ++e) o[e] = fmaxf(o[e], 0.f);
        }
        uint4 pv;
        pv.x = (unsigned int)f2bf(o[0]) | ((unsigned int)f2bf(o[1]) << 16);
        pv.y = (unsigned int)f2bf(o[2]) | ((unsigned int)f2bf(o[3]) << 16);
        pv.z = (unsigned int)f2bf(o[4]) | ((unsigned int)f2bf(o[5]) << 16);
        pv.w = (unsigned int)f2bf(o[6]) | ((unsigned int)f2bf(o[7]) << 16);
        *(uint4*)(out + (size_t)grow * FDIM + gc) = pv;
    }
}

// ---------------------------------------------------------------------------
// CSR decoder, quarter-wave, 2 queries per quarter (8/wave per iteration).
// ---------------------------------------------------------------------------
__global__ __launch_bounds__(256) void k_decoder_csr(const unsigned short* __restrict__ zS,
                                                     const unsigned short* __restrict__ zM,
                                                     const int* __restrict__ qbeg,
                                                     const int* __restrict__ qdeg,
                                                     const uint2* __restrict__ qdat,
                                                     float* __restrict__ out) {
    int c = (blockIdx.x * 256 + threadIdx.x) >> 6;
    int l = threadIdx.x & 63;
    if (c >= N_MRNA) return;
    int cnt = qdeg[c];
    if (cnt == 0) return;
    int beg = qbeg[c];
    const int q = l >> 4, lq = l & 15;

    bf16x8 vm = *(const bf16x8*)(zM + (size_t)c * FDIM + lq * 8);
    float mxf[8];
#pragma unroll
    for (int k = 0; k < 8; ++k) mxf[k] = bf2f((unsigned short)vm[k]);

    for (int e = 0; e < cnt; e += 8) {
        bool val0 = (e + q) < cnt;
        bool val1 = (e + 4 + q) < cnt;
        uint2 d0 = qdat[beg + min(e + q, cnt - 1)];
        uint2 d1 = qdat[beg + min(e + 4 + q, cnt - 1)];
        bf16x8 va0 = *(const bf16x8*)(zS + (size_t)d0.x * FDIM + lq * 8);
        bf16x8 va1 = *(const bf16x8*)(zS + (size_t)d1.x * FDIM + lq * 8);
        float s0 = 0.f, s1 = 0.f;
#pragma unroll
        for (int k = 0; k < 8; ++k) {
            s0 += bf2f((unsigned short)va0[k]) * mxf[k];
            s1 += bf2f((unsigned short)va1[k]) * mxf[k];
        }
        s0 += __shfl_xor(s0, 1);  s1 += __shfl_xor(s1, 1);
        s0 += __shfl_xor(s0, 2);  s1 += __shfl_xor(s1, 2);
        s0 += __shfl_xor(s0, 4);  s1 += __shfl_xor(s1, 4);
        s0 += __shfl_xor(s0, 8);  s1 += __shfl_xor(s1, 8);
        if (lq == 0) {
            if (val0) out[d0.y] = s0;
            if (val1) out[d1.y] = s1;
        }
    }
}

// ---------------------------------------------------------------------------
// Launch
// ---------------------------------------------------------------------------
extern "C" void kernel_launch(void* const* d_in, const int* in_sizes, int n_in,
                              void* d_out, int out_size, void* d_ws, size_t ws_size,
                              hipStream_t stream) {
    const float* x_srna = (const float*)d_in[0];
    const float* x_mrna = (const float*)d_in[1];
    const int* src_sm = (const int*)d_in[2];
    const int* dst_sm = (const int*)d_in[3];
    const int* src_ms = (const int*)d_in[4];
    const int* dst_ms = (const int*)d_in[5];
    const int* lbl_row = (const int*)d_in[6];
    const int* lbl_col = (const int*)d_in[7];
    const float* W1l_sm = (const float*)d_in[8];
    const float* W1r_sm = (const float*)d_in[9];
    const float* W1l_ms = (const float*)d_in[10];
    const float* W1r_ms = (const float*)d_in[11];
    const float* W2l_sm = (const float*)d_in[12];
    const float* W2r_sm = (const float*)d_in[13];
    const float* W2l_ms = (const float*)d_in[14];
    const float* W2r_ms = (const float*)d_in[15];
    const float* b1_sm = (const float*)d_in[16];
    const float* b1_ms = (const float*)d_in[17];
    const float* b2_sm = (const float*)d_in[18];
    const float* b2_ms = (const float*)d_in[19];
    float* out = (float*)d_out;

    // Workspace layout (16B aligned)
    char* ws = (char*)d_ws;
    unsigned short* xS_bf   = (unsigned short*)(ws + 0);           //   5,120,000
    unsigned short* xM_bf   = (unsigned short*)(ws + 5120000);     //  25,600,000
    unsigned short* meanM   = (unsigned short*)(ws + 30720000);    //  25,600,000 (becomes zM)
    unsigned short* meanS   = (unsigned short*)(ws + 56320000);    //   5,120,000 (becomes zS)
    unsigned short* hM_bf   = (unsigned short*)(ws + 61440000);    //  25,600,000
    unsigned short* hS_bf   = (unsigned short*)(ws + 87040000);    //   5,120,000
    unsigned short* Wt1sm   = (unsigned short*)(ws + 92160000);    //      65,536
    unsigned short* Wt1ms   = (unsigned short*)(ws + 92225536);    //      65,536
    unsigned short* Wt2sm   = (unsigned short*)(ws + 92291072);    //      65,536
    unsigned short* Wt2ms   = (unsigned short*)(ws + 92356608);    //      65,536
    int* begd               = (int*)(ws + 92422144);               //     480,000
    int* degd               = (int*)(ws + 92902144);               //     480,000
    int* col_all            = (int*)(ws + 93382144);               //  11,567,104 (353*8192*4)
    unsigned int* recs      = (unsigned int*)(ws + 104949248);     //  11,567,104
    uint2* qrecs            = (uint2*)(ws + 116516352);            //   6,422,528 (196*4096*8)
    uint2* qdat             = (uint2*)(ws + 122938880);            //   6,422,528
    int* qbeg               = (int*)(ws + 129361408);              //     400,000
    int* qdeg               = (int*)(ws + 129761408);              //     400,000
    int* bcur               = (int*)(ws + 130161408);              //       1,412 (353 ints)
    int* qbcur              = (int*)(ws + 130162820);              //         784 (196 ints)
    // total ~130.2 MB

    // --- merged dtype prep (wt build + cvt in one dispatch) ---
    k_prep<<<2560, 256, 0, stream>>>(x_srna, x_mrna, xS_bf, xM_bf,
                                     W1l_sm, W1r_sm, Wt1sm,
                                     W1l_ms, W1r_ms, Wt1ms,
                                     W2l_sm, W2r_sm, Wt2sm,
                                     W2l_ms, W2r_ms, Wt2ms);

    // --- zero both cursor arrays with ONE memset (adjacent) ---
    hipMemsetAsync(bcur, 0, (NB + NB_Q) * sizeof(int), stream);

    // --- Combined edge + query binning, then combined finalize ---
    k_scatter_all<<<NBLK_E + NBLK_Q, 256, 0, stream>>>(src_sm, dst_sm, src_ms, dst_ms,
                                                       lbl_row, lbl_col, bcur, qbcur,
                                                       recs, qrecs);
    k_build_all<<<NB + NB_Q, 256, 0, stream>>>(recs, bcur, qrecs, qbcur,
                                               begd, degd, col_all, qbeg, qdeg, qdat);

    const int nblk_m = (N_MRNA + 127) / 128;               // 782
    const int nblk_s = (N_SRNA + 127) / 128;               // 157
    // waves: 12500 mrna (8 rows/wave) + 20000 srna (1 row/wave) = 32500
    const int segblk = (N_MRNA / 8 + N_SRNA + 3) / 4;      // 8125 blocks (4 waves each)

    // --- Layer 1 (fused node types) ---
    k_seg_mean2<<<segblk, 256, 0, stream>>>(xS_bf, xM_bf, begd, degd, col_all,
                                            meanM, meanS, N_MRNA, NDST_ALL);
    k_gemm_mfma2<true><<<nblk_m + nblk_s, 256, 0, stream>>>(
        meanM, xM_bf, Wt1sm, b1_sm, hM_bf, N_MRNA, nblk_m,
        meanS, xS_bf, Wt1ms, b1_ms, hS_bf, N_SRNA);

    // --- Layer 2 (z overwrites mean buffers in place) ---
    k_seg_mean2<<<segblk, 256, 0, stream>>>(hS_bf, hM_bf, begd, degd, col_all,
                                            meanM, meanS, N_MRNA, NDST_ALL);
    k_gemm_mfma2<false><<<nblk_m + nblk_s, 256, 0, stream>>>(
        meanM, hM_bf, Wt2sm, b2_sm, meanM, N_MRNA, nblk_m,
        meanS, hS_bf, Wt2ms, b2_ms, meanS, N_SRNA);

    // --- Decoder ---
    k_decoder_csr<<<(N_MRNA + 3) / 4, 256, 0, stream>>>(meanS, meanM, qbeg, qdeg, qdat, out);
}